// Round 16
// baseline (2475.621 us; speedup 1.0000x reference)
//
#include <hip/hip_runtime.h>
#include <math.h>

#define BATCH   32
#define SEQ     197
#define HIDDEN  768
#define NHEADS  12
#define DHEAD   64
#define NBLOCKS 12
#define MLP_D   3072
#define OUTD    1000
#define NPATCH  196
#define M_TOK   (BATCH*SEQ)      // 6304
#define M_PAD   6400             // padded rows for fp16 activation buffers
#define LN_EPS  1e-5f
#define SP      208              // padded seq (13*16)

typedef _Float16 f16;
typedef _Float16 f16x8 __attribute__((ext_vector_type(8)));
typedef _Float16 f16x4 __attribute__((ext_vector_type(4)));
typedef float    f32x4 __attribute__((ext_vector_type(4)));

__device__ __forceinline__ float gelu_exact(float x) {
    return 0.5f * x * (1.0f + erff(x * 0.70710678118654752f));
}

__device__ __forceinline__ void gload_lds16(const void* g, void* l) {
    __builtin_amdgcn_global_load_lds(
        (const __attribute__((address_space(1))) void*)g,
        (__attribute__((address_space(3))) void*)l, 16, 0, 0);
}

// swizzled LDS read for 128B-stride rows (8 slots): slot XOR (row&7) — bijective
__device__ __forceinline__ f16x8 lds_ld(const char* base, int row, int rs, int kbyte) {
    return *(const f16x8*)(base + row*rs + (kbyte ^ ((row & 7) << 4)));
}

// BK=32 packed layout: physical row p (128B, 8 slots) holds logical rows 2p (slots 0-3)
// and 2p+1 (slots 4-7), slots XOR'd by (p&7). Fragment read: logical row r, k-chunk lg.
__device__ __forceinline__ f16x8 lds32(const char* buf, int row, int lg) {
    int p = row >> 1;
    int sl = (((row & 1) << 2) + lg) ^ (p & 7);
    return *(const f16x8*)(buf + p*128 + sl*16);
}

// ---------- patchify ----------
__global__ __launch_bounds__(256) void patchify_kernel(const float* __restrict__ x,
                                                       f16* __restrict__ patches) {
    int row = blockIdx.x;
    int n = row / NPATCH;
    int p = row % NPATCH;
    int pi = p / 14, pj = p % 14;
    for (int k = threadIdx.x; k < 768; k += 256) {
        int c   = k >> 8;
        int r   = (k >> 4) & 15;
        int col = k & 15;
        patches[(size_t)row*768 + k] =
            (f16)x[(((size_t)n*3 + c)*224 + (pi*16 + r))*224 + pj*16 + col];
    }
}

// ---------- batched fp32 [R][C] -> f16 transposed [C][R], 64x64 tiles, z = layer ----------
__global__ __launch_bounds__(256) void transT_kernel(const float* __restrict__ src,
                                                     f16* __restrict__ dst,
                                                     int R, int C) {
    const float* in = src + (size_t)blockIdx.z * R * C;
    f16* out = dst + (size_t)blockIdx.z * R * C;
    __shared__ float tile[64][65];
    int r0 = blockIdx.y * 64, c0 = blockIdx.x * 64;
    int t = threadIdx.x;
    int lr16 = t >> 4, lc4 = (t & 15) * 4;
    #pragma unroll
    for (int i = 0; i < 4; ++i) {
        int r = i*16 + lr16;
        float4 v = *(const float4*)&in[(size_t)(r0 + r)*C + c0 + lc4];
        tile[r][lc4] = v.x; tile[r][lc4+1] = v.y; tile[r][lc4+2] = v.z; tile[r][lc4+3] = v.w;
    }
    __syncthreads();
    #pragma unroll
    for (int i = 0; i < 4; ++i) {
        int c = i*16 + lr16;
        int r = lc4;
        f16x4 pv = { (f16)tile[r][c], (f16)tile[r+1][c], (f16)tile[r+2][c], (f16)tile[r+3][c] };
        *(f16x4*)&out[(size_t)(c0 + c)*R + r0 + r] = pv;
    }
}

// ---------- dual transpose (fallback path) ----------
__global__ __launch_bounds__(256) void convtrans2_kernel(const float* __restrict__ W1,
                                                         const float* __restrict__ W2,
                                                         f16* __restrict__ W1T,
                                                         f16* __restrict__ W2T) {
    int z = blockIdx.z;
    const float* in = z ? W2 : W1;
    f16* out = z ? W2T : W1T;
    int R = z ? MLP_D : HIDDEN;
    int C = z ? HIDDEN : MLP_D;
    int bx = z ? blockIdx.y : blockIdx.x;
    int by = z ? blockIdx.x : blockIdx.y;
    __shared__ float tile[32][33];
    int r0 = by * 32, c0 = bx * 32;
    int tx = threadIdx.x & 31, ty = threadIdx.x >> 5;
    #pragma unroll
    for (int i = 0; i < 4; ++i) {
        int r = ty + i*8;
        tile[r][tx] = in[(size_t)(r0 + r)*C + c0 + tx];
    }
    __syncthreads();
    #pragma unroll
    for (int i = 0; i < 4; ++i) {
        int r = ty + i*8;
        out[(size_t)(c0 + r)*R + r0 + tx] = (f16)tile[tx][r];
    }
}

// ---------- QKV weight transpose ----------
__global__ __launch_bounds__(256) void qkvtrans_kernel(const float* __restrict__ Wq,
                                                       const float* __restrict__ Wk,
                                                       const float* __restrict__ Wv,
                                                       f16* __restrict__ outT) {
    int b = blockIdx.x;
    int blkL = b / 36, rem = b % 36;
    int hh = rem / 3, mat = rem % 3;
    const float* in = (mat == 0 ? Wq : mat == 1 ? Wk : Wv) + ((size_t)(blkL*12 + hh))*4096;
    f16* out = outT + (size_t)b * 4096;
    __shared__ float tile[64][65];
    int t = threadIdx.x;
    for (int i = t; i < 4096; i += 256) tile[i >> 6][i & 63] = in[i];
    __syncthreads();
    for (int i = t; i < 4096; i += 256) out[i] = (f16)tile[i & 63][i >> 6];
}

// ---------- assemble ----------
__global__ __launch_bounds__(256) void assemble_kernel(const float* __restrict__ tokens,
                                                       const float* __restrict__ cls,
                                                       const float* __restrict__ pos,
                                                       float* __restrict__ h) {
    int r = blockIdx.x;
    int n = r / SEQ, s = r % SEQ;
    for (int c = threadIdx.x; c < 768; c += 256) {
        float v = (s == 0) ? cls[c] : tokens[(size_t)(n*NPATCH + s - 1)*768 + c];
        h[(size_t)r*768 + c] = v + pos[s*768 + c];
    }
}

// ---------- dual layernorm v2 (validated round 12) ----------
__global__ __launch_bounds__(256) void layernorm2_kernel(const float* __restrict__ x,
                                                         const float* __restrict__ s1,
                                                         const float* __restrict__ b1,
                                                         const float* __restrict__ s2,
                                                         const float* __restrict__ b2,
                                                         f16* __restrict__ o1,
                                                         f16* __restrict__ o2) {
    int wid = threadIdx.x >> 6, lane = threadIdx.x & 63;
    int r = blockIdx.x * 4 + wid;             // M_TOK = 1576*4 exact
    const float4* xr = (const float4*)(x + (size_t)r * 768);
    float4 v[3];
    v[0] = xr[lane]; v[1] = xr[lane + 64]; v[2] = xr[lane + 128];
    float s = v[0].x+v[0].y+v[0].z+v[0].w + v[1].x+v[1].y+v[1].z+v[1].w
            + v[2].x+v[2].y+v[2].z+v[2].w;
    #pragma unroll
    for (int off = 32; off > 0; off >>= 1) s += __shfl_xor(s, off);
    float mean = s * (1.0f/768.0f);
    float q = 0.f;
    #pragma unroll
    for (int j = 0; j < 3; ++j) {
        float a = v[j].x-mean, b = v[j].y-mean, c = v[j].z-mean, d = v[j].w-mean;
        q += a*a + b*b + c*c + d*d;
    }
    #pragma unroll
    for (int off = 32; off > 0; off >>= 1) q += __shfl_xor(q, off);
    float inv = rsqrtf(q * (1.0f/768.0f) + LN_EPS);
    #pragma unroll
    for (int j = 0; j < 3; ++j) {
        int col = (lane + 64*j) * 4;
        float4 sc1 = *(const float4*)(s1 + col);
        float4 bb1 = *(const float4*)(b1 + col);
        float4 sc2 = *(const float4*)(s2 + col);
        float4 bb2 = *(const float4*)(b2 + col);
        float a = (v[j].x-mean)*inv, b = (v[j].y-mean)*inv,
              c = (v[j].z-mean)*inv, d = (v[j].w-mean)*inv;
        f16x4 w1 = { (f16)(a*sc1.x+bb1.x), (f16)(b*sc1.y+bb1.y),
                     (f16)(c*sc1.z+bb1.z), (f16)(d*sc1.w+bb1.w) };
        f16x4 w2 = { (f16)(a*sc2.x+bb2.x), (f16)(b*sc2.y+bb2.y),
                     (f16)(c*sc2.z+bb2.z), (f16)(d*sc2.w+bb2.w) };
        *(f16x4*)(o1 + (size_t)r*768 + col) = w1;
        *(f16x4*)(o2 + (size_t)r*768 + col) = w2;
    }
}

// ---------- fused QKV + attention v2 (validated round 12) ----------
__global__ __launch_bounds__(512) void fused_attn_kernel(
        const f16* __restrict__ lnh, const f16* __restrict__ qkvT,
        const float* __restrict__ bq, const float* __restrict__ bk,
        const float* __restrict__ bv, float* __restrict__ O) {
    int n = blockIdx.x, h = blockIdx.y;
    int t = threadIdx.x, wid = t >> 6, lane = t & 63;
    int lr = lane & 15;
    int lg = lane >> 4;

    __shared__ char lds[153600];
    char* Xs  = lds;
    char* Qs  = lds + 26624;
    char* Ks  = lds + 53248;
    char* VsT = lds + 79872;
    char* Ws  = lds + 112640;
    char* Ps  = (wid < 3) ? (lds + wid*8192)
              : (wid < 6) ? (lds + 112640 + (wid-3)*8192)
                          : (lds + 137216 + (wid-6)*8192);

    const char* xsrc = (const char*)(lnh + (size_t)n*SEQ*768 + h*64);
    for (int c = t; c < SP*8; c += 512) {
        int s = c >> 3, kb = (c & 7) * 16;
        f16x8 v = {};
        if (s < SEQ) v = *(const f16x8*)(xsrc + (size_t)s*1536 + kb);
        *(f16x8*)(Xs + s*128 + (kb ^ ((s & 7) << 4))) = v;
    }
    const char* wsrc = (const char*)(qkvT) + (size_t)h * 3 * 4096 * 2;
    for (int c = t; c < 1536; c += 512) {
        int byte = c * 16, row = byte >> 7, kb = byte & 127;
        f16x8 v = *(const f16x8*)(wsrc + byte);
        *(f16x8*)(Ws + row*128 + (kb ^ ((row & 7) << 4))) = v;
    }
    for (int c = t; c < 384; c += 512) {
        int e = c / 6, sl = c % 6;
        int kb = 416 + sl * 16;
        *(f16x8*)(VsT + e*512 + (kb ^ ((e & 7) << 4))) = (f16x8){};
    }
    __syncthreads();

    for (int idx = wid; idx < 39; idx += 8) {
        int mat = idx / 13, mt = idx % 13;
        const float* bias = (mat == 0) ? bq : (mat == 1) ? bk : bv;
        #pragma unroll
        for (int nt = 0; nt < 4; ++nt) {
            f32x4 acc = {};
            #pragma unroll
            for (int ks = 0; ks < 2; ++ks) {
                f16x8 a = lds_ld(Xs, mt*16 + lr, 128, lg*16 + ks*64);
                f16x8 b = lds_ld(Ws, mat*64 + nt*16 + lr, 128, lg*16 + ks*64);
                acc = __builtin_amdgcn_mfma_f32_16x16x32_f16(a, b, acc, 0, 0, 0);
            }
            float bb = bias[h*64 + nt*16 + lr];
            if (mat < 2) {
                char* dst = (mat == 0) ? Qs : Ks;
                #pragma unroll
                for (int j = 0; j < 4; ++j) {
                    int s = mt*16 + lg*4 + j;
                    int eb = (nt*16 + lr) * 2;
                    *(f16*)(dst + s*128 + (eb ^ ((s & 7) << 4))) = (f16)(acc[j] + bb);
                }
            } else {
                int e = nt*16 + lr;
                int sb = (mt*16 + lg*4) * 2;
                f16x4 pv;
                #pragma unroll
                for (int j = 0; j < 4; ++j) pv[j] = (f16)(acc[j] + bb);
                *(f16x4*)(VsT + e*512 + (sb ^ ((e & 7) << 4))) = pv;
            }
        }
    }
    __syncthreads();

    for (int c = lane; c < 96; c += 64) {
        int r = c / 6, kb = 416 + (c % 6) * 16;
        *(f16x8*)(Ps + r*512 + (kb ^ ((r & 7) << 4))) = (f16x8){};
    }

    const float scale = 0.28867513459481288f;   // 1/sqrt(12)
    for (int mt = wid; mt < 13; mt += 8) {
        f32x4 sacc[13];
        #pragma unroll
        for (int nt = 0; nt < 13; ++nt) sacc[nt] = (f32x4){};
        #pragma unroll
        for (int ks = 0; ks < 2; ++ks) {
            f16x8 a = lds_ld(Qs, mt*16 + lr, 128, lg*16 + ks*64);
            #pragma unroll
            for (int nt = 0; nt < 13; ++nt) {
                f16x8 b = lds_ld(Ks, nt*16 + lr, 128, lg*16 + ks*64);
                sacc[nt] = __builtin_amdgcn_mfma_f32_16x16x32_f16(a, b, sacc[nt], 0, 0, 0);
            }
        }
        float mx0 = -1e30f, mx1 = -1e30f, mx2 = -1e30f, mx3 = -1e30f;
        #pragma unroll
        for (int nt = 0; nt < 13; ++nt) {
            bool valid = (nt*16 + lr) < SEQ;
            #pragma unroll
            for (int j = 0; j < 4; ++j) {
                float v = valid ? sacc[nt][j] * scale : -1e30f;
                sacc[nt][j] = v;
            }
            mx0 = fmaxf(mx0, sacc[nt][0]); mx1 = fmaxf(mx1, sacc[nt][1]);
            mx2 = fmaxf(mx2, sacc[nt][2]); mx3 = fmaxf(mx3, sacc[nt][3]);
        }
        #pragma unroll
        for (int off = 1; off < 16; off <<= 1) {
            mx0 = fmaxf(mx0, __shfl_xor(mx0, off));
            mx1 = fmaxf(mx1, __shfl_xor(mx1, off));
            mx2 = fmaxf(mx2, __shfl_xor(mx2, off));
            mx3 = fmaxf(mx3, __shfl_xor(mx3, off));
        }
        float s0 = 0.f, s1 = 0.f, s2 = 0.f, s3 = 0.f;
        #pragma unroll
        for (int nt = 0; nt < 13; ++nt) {
            float p0 = expf(sacc[nt][0] - mx0); sacc[nt][0] = p0; s0 += p0;
            float p1 = expf(sacc[nt][1] - mx1); sacc[nt][1] = p1; s1 += p1;
            float p2 = expf(sacc[nt][2] - mx2); sacc[nt][2] = p2; s2 += p2;
            float p3 = expf(sacc[nt][3] - mx3); sacc[nt][3] = p3; s3 += p3;
        }
        #pragma unroll
        for (int off = 1; off < 16; off <<= 1) {
            s0 += __shfl_xor(s0, off); s1 += __shfl_xor(s1, off);
            s2 += __shfl_xor(s2, off); s3 += __shfl_xor(s3, off);
        }
        float i0 = 1.0f/s0, i1 = 1.0f/s1, i2 = 1.0f/s2, i3 = 1.0f/s3;
        #pragma unroll
        for (int nt = 0; nt < 13; ++nt) {
            int cb = (nt*16 + lr) * 2;
            { int r = lg*4 + 0; *(f16*)(Ps + r*512 + (cb ^ ((r & 7) << 4))) = (f16)(sacc[nt][0] * i0); }
            { int r = lg*4 + 1; *(f16*)(Ps + r*512 + (cb ^ ((r & 7) << 4))) = (f16)(sacc[nt][1] * i1); }
            { int r = lg*4 + 2; *(f16*)(Ps + r*512 + (cb ^ ((r & 7) << 4))) = (f16)(sacc[nt][2] * i2); }
            { int r = lg*4 + 3; *(f16*)(Ps + r*512 + (cb ^ ((r & 7) << 4))) = (f16)(sacc[nt][3] * i3); }
        }
        f32x4 oacc[4] = {};
        #pragma unroll
        for (int ks = 0; ks < 8; ++ks) {
            f16x8 a = lds_ld(Ps, lr, 512, lg*16 + ks*64);
            #pragma unroll
            for (int nt = 0; nt < 4; ++nt) {
                f16x8 b = lds_ld(VsT, nt*16 + lr, 512, lg*16 + ks*64);
                oacc[nt] = __builtin_amdgcn_mfma_f32_16x16x32_f16(a, b, oacc[nt], 0, 0, 0);
            }
        }
        #pragma unroll
        for (int nt = 0; nt < 4; ++nt) {
            #pragma unroll
            for (int j = 0; j < 4; ++j) {
                int s = mt*16 + lg*4 + j;
                if (s < SEQ)
                    O[((size_t)(n*SEQ + s))*768 + h*64 + nt*16 + lr] = oacc[nt][j];
            }
        }
    }
}

// ---------- fp16 MFMA GEMM (round-12 validated, NO phase rotation) ----------
template<int MODE, int TN>
__global__ __launch_bounds__(256) void hgemm_kernel(
        const f16* __restrict__ A, const f16* __restrict__ BT,
        const float* __restrict__ bias,
        const float* __restrict__ res1, const float* __restrict__ res2,
        void* __restrict__ Cout, int M, int N, int K, int nbx) {
    constexpr int BISS = TN / 64;
    constexpr int WN   = TN / 2;
    constexpr int NFR  = WN / 16;
    __shared__ f16 As[2][128*32];
    __shared__ f16 Bs[2][TN*32];
    int t = threadIdx.x;
    int wid = t >> 6, lane = t & 63;
    int lr = lane & 15, lg = lane >> 4;
    int wr = wid >> 1, wc = wid & 1;

    int nwg = gridDim.x, bid = blockIdx.x;
    int q = nwg >> 3, r = nwg & 7;
    int xcd = bid & 7, idx = bid >> 3;
    int swz = (xcd < r) ? xcd*(q+1) + idx : r*(q+1) + (xcd-r)*q + idx;
    int bn = (swz % nbx) * TN;
    int bm = (swz / nbx) * 128;

    int agrow[2], agk[2], bgrow[BISS], bgk[BISS];
    #pragma unroll
    for (int i = 0; i < 2; ++i) {
        int fb = i*4096 + wid*1024 + lane*16;
        int p = fb >> 7, u = ((fb >> 4) & 7) ^ (p & 7);
        agrow[i] = 2*p + (u >> 2); agk[i] = (u & 3) * 8;
    }
    #pragma unroll
    for (int i = 0; i < BISS; ++i) {
        int fb = i*4096 + wid*1024 + lane*16;
        int p = fb >> 7, u = ((fb >> 4) & 7) ^ (p & 7);
        bgrow[i] = 2*p + (u >> 2); bgk[i] = (u & 3) * 8;
    }

    #define STAGE(P, K0)                                                          \
        do {                                                                      \
            _Pragma("unroll")                                                     \
            for (int i = 0; i < 2; ++i)                                           \
                gload_lds16(A + (size_t)(bm + agrow[i])*K + (K0) + agk[i],        \
                            (char*)&As[P][0] + i*4096 + wid*1024);                \
            _Pragma("unroll")                                                     \
            for (int i = 0; i < BISS; ++i)                                        \
                gload_lds16(BT + (size_t)(bn + bgrow[i])*K + (K0) + bgk[i],       \
                            (char*)&Bs[P][0] + i*4096 + wid*1024);                \
        } while (0)

    f32x4 acc[4][NFR] = {};
    int nk = K >> 5;

    STAGE(0, 0);
    __syncthreads();
    for (int kt = 0; kt < nk; ++kt) {
        int cur = kt & 1;
        if (kt + 1 < nk) STAGE(cur ^ 1, (kt + 1) * 32);
        const char* Ab = (const char*)&As[cur][0];
        const char* Bb = (const char*)&Bs[cur][0];
        f16x8 a[4], b[NFR];
        #pragma unroll
        for (int m = 0; m < 4; ++m)
            a[m] = lds32(Ab, wr*64 + m*16 + lr, lg);
        #pragma unroll
        for (int nn = 0; nn < NFR; ++nn)
            b[nn] = lds32(Bb, wc*WN + nn*16 + lr, lg);
        #pragma unroll
        for (int m = 0; m < 4; ++m)
            #pragma unroll
            for (int nn = 0; nn < NFR; ++nn)
                acc[m][nn] = __builtin_amdgcn_mfma_f32_16x16x32_f16(a[m], b[nn], acc[m][nn], 0, 0, 0);
        __syncthreads();
    }
    #undef STAGE

    int row0 = bm + wr*64 + lg*4;
    int col0 = bn + wc*WN + lr;
    #pragma unroll
    for (int m = 0; m < 4; ++m) {
        #pragma unroll
        for (int nn = 0; nn < NFR; ++nn) {
            int col = col0 + nn*16;
            float bv = bias[col];
            #pragma unroll
            for (int j = 0; j < 4; ++j) {
                int row = row0 + m*16 + j;
                if (row >= M) continue;
                float v = acc[m][nn][j] + bv;
                size_t idx = (size_t)row*N + col;
                if (MODE == 0) {
                    if (res1) v += res1[idx] + res2[idx];
                    ((float*)Cout)[idx] = v;
                } else {
                    ((f16*)Cout)[idx] = (f16)gelu_exact(v);
                }
            }
        }
    }
}

// ---------- hgemm9b: 256x128, BK=32, 3-buffer counted-vmcnt pipeline, 72 KB LDS ----------
// r13's validated sync structure (vmcnt(3) + single raw barrier per K-tile), with BK
// halved so 2 blocks/CU fit: MLP1's 600 blocks = 1.17 fills instead of 2.34.
__global__ __launch_bounds__(512) void hgemm9b_kernel(
        const f16* __restrict__ A,    // [>=bm+256][K] (padded rows)
        const f16* __restrict__ BT,   // [N][K]
        const float* __restrict__ bias,
        f16* __restrict__ Cout,       // gelu -> f16
        int M, int N, int K, int nbx) {
    __shared__ f16 As[3][256*32];     // phys [128][128B] packed, 3 x 16 KB
    __shared__ f16 Bs[3][128*32];     // phys [64][128B],  3 x 8 KB
    int t = threadIdx.x;
    int wid = t >> 6, lane = t & 63;
    int lr = lane & 15, lg = lane >> 4;
    int wr = wid >> 2, wc = wid & 3;  // 2x4 wave grid; wave tile 128x32

    int nwg = gridDim.x, bid = blockIdx.x;
    int q = nwg >> 3, r = nwg & 7;
    int xcd = bid & 7, idx = bid >> 3;
    int swz = (xcd < r) ? xcd*(q+1) + idx : r*(q+1) + (xcd-r)*q + idx;
    int bn = (swz % nbx) * 128;
    int bm = (swz / nbx) * 256;

    // packed staging geometry: LDS byte fb -> phys p=fb>>7, slot s=(fb>>4)&7;
    // unswizzled u = s^(p&7) -> global row 2p+(u>>2), k-chunk (u&3)*8 f16
    int agrow[2], agk[2], bgrow, bgk;
    #pragma unroll
    for (int i = 0; i < 2; ++i) {
        int fb = i*8192 + t*16;
        int p = fb >> 7, u = ((fb >> 4) & 7) ^ (p & 7);
        agrow[i] = 2*p + (u >> 2); agk[i] = (u & 3) * 8;
    }
    {
        int fb = t*16;
        int p = fb >> 7, u = ((fb >> 4) & 7) ^ (p & 7);
        bgrow = 2*p + (u >> 2); bgk = (u & 3) * 8;
    }

    #define STAGE9(P, K0)                                                         \
        do {                                                                      \
            _Pragma("unroll")                                                     \
            for (int i = 0; i < 2; ++i)                                           \
                gload_lds16(A + (size_t)(bm + agrow[i])*K + (K0) + agk[i],        \
                            (char*)&As[P][0] + i*8192 + wid*1024);                \
            gload_lds16(BT + (size_t)(bn + bgrow)*K + (K0) + bgk,                 \
                        (char*)&Bs[P][0] + wid*1024);                             \
        } while (0)

    f32x4 acc[8][2] = {};
    int nk = K >> 5;                  // 24 for K=768

    STAGE9(0, 0);
    STAGE9(1, 32);
    for (int kt = 0; kt < nk; ++kt) {
        int cur = kt % 3;
        if (kt + 1 < nk) asm volatile("s_waitcnt vmcnt(3)" ::: "memory");
        else             asm volatile("s_waitcnt vmcnt(0)" ::: "memory");
        __builtin_amdgcn_s_barrier();
        asm volatile("" ::: "memory");
        if (kt + 2 < nk) STAGE9((kt + 2) % 3, (kt + 2) * 32);
        const char* Ab = (const char*)&As[cur][0];
        const char* Bb = (const char*)&Bs[cur][0];
        f16x8 a[8], b[2];
        #pragma unroll
        for (int nn = 0; nn < 2; ++nn)
            b[nn] = lds32(Bb, wc*32 + nn*16 + lr, lg);
        #pragma unroll
        for (int m = 0; m < 8; ++m)
            a[m] = lds32(Ab, wr*128 + m*16 + lr, lg);
        #pragma unroll
        for (int m = 0; m < 8; ++m)
            #pragma unroll
            for (int nn = 0; nn < 2; ++nn)
                acc[m][nn] = __builtin_amdgcn_mfma_f32_16x16x32_f16(a[m], b[nn], acc[m][nn], 0, 0, 0);
        asm volatile("" ::: "memory");
    }
    #undef STAGE9

    int row0 = bm + wr*128 + lg*4;
    int col0 = bn + wc*32 + lr;
    #pragma unroll
    for (int m = 0; m < 8; ++m) {
        #pragma unroll
        for (int nn = 0; nn < 2; ++nn) {
            int col = col0 + nn*16;
            float bv = bias[col];
            #pragma unroll
            for (int j = 0; j < 4; ++j) {
                int row = row0 + m*16 + j;
                if (row >= M) continue;
                Cout[(size_t)row*N + col] = (f16)gelu_exact(acc[m][nn][j] + bv);
            }
        }
    }
}

// ---------- fused classifier head ----------
__global__ __launch_bounds__(256) void head_kernel(const float* __restrict__ h,
                                                   const float* __restrict__ W_out,
                                                   const float* __restrict__ b_out,
                                                   float* __restrict__ out) {
    int n = blockIdx.x, t = threadIdx.x;
    __shared__ float xs[HIDDEN];
    __shared__ float red[4];
    const float* hr = h + (size_t)n*SEQ*HIDDEN;
    for (int k = t; k < HIDDEN; k += 256) xs[k] = hr[k];
    __syncthreads();

    bool v3 = t < (OUTD - 768);
    int c3 = v3 ? (t + 768) : t;
    float a0 = 0.f, a1 = 0.f, a2 = 0.f, a3 = 0.f;
    #pragma unroll 8
    for (int k = 0; k < HIDDEN; ++k) {
        float xv = xs[k];
        const float* wr = W_out + (size_t)k*OUTD;
        a0 = fmaf(xv, wr[t],       a0);
        a1 = fmaf(xv, wr[t + 256], a1);
        a2 = fmaf(xv, wr[t + 512], a2);
        a3 = fmaf(xv, wr[c3],      a3);
    }
    a0 += b_out[t]; a1 += b_out[t + 256]; a2 += b_out[t + 512];
    a3 = v3 ? (a3 + b_out[t + 768]) : -1e30f;

    int wid = t >> 6, lane = t & 63;
    float mx = fmaxf(fmaxf(a0, a1), fmaxf(a2, a3));
    #pragma unroll
    for (int off = 32; off > 0; off >>= 1) mx = fmaxf(mx, __shfl_xor(mx, off));
    if (lane == 0) red[wid] = mx;
    __syncthreads();
    mx = fmaxf(fmaxf(red[0], red[1]), fmaxf(red[2], red[3]));
    __syncthreads();

    float p0 = expf(a0 - mx), p1 = expf(a1 - mx), p2 = expf(a2 - mx);
    float p3 = v3 ? expf(a3 - mx) : 0.f;
    float s = p0 + p1 + p2 + p3;
    #pragma unroll
    for (int off = 32; off > 0; off >>= 1) s += __shfl_xor(s, off);
    if (lane == 0) red[wid] = s;
    __syncthreads();
    s = red[0] + red[1] + red[2] + red[3];
    float inv = 1.0f / s;

    float* orow = out + (size_t)n*OUTD;
    orow[t]       = p0 * inv;
    orow[t + 256] = p1 * inv;
    orow[t + 512] = p2 * inv;
    if (v3) orow[t + 768] = p3 * inv;
}

extern "C" void kernel_launch(void* const* d_in, const int* in_sizes, int n_in,
                              void* d_out, int out_size, void* d_ws, size_t ws_size,
                              hipStream_t stream) {
    const float* x     = (const float*)d_in[0];
    const float* W_map = (const float*)d_in[1];
    const float* b_map = (const float*)d_in[2];
    const float* cls_t = (const float*)d_in[3];
    const float* pos   = (const float*)d_in[4];
    const float* ln1_s = (const float*)d_in[5];
    const float* ln1_b = (const float*)d_in[6];
    const float* Wq    = (const float*)d_in[7];
    const float* bq    = (const float*)d_in[8];
    const float* Wk    = (const float*)d_in[9];
    const float* bk    = (const float*)d_in[10];
    const float* Wv    = (const float*)d_in[11];
    const float* bv    = (const float*)d_in[12];
    const float* ln2_s = (const float*)d_in[13];
    const float* ln2_b = (const float*)d_in[14];
    const float* W1    = (const float*)d_in[15];
    const float* b1    = (const float*)d_in[16];
    const float* W2    = (const float*)d_in[17];
    const float* b2    = (const float*)d_in[18];
    const float* W_out = (const float*)d_in[19];
    const float* b_out = (const float*)d_in[20];
    float* out = (float*)d_out;

    const size_t LAYER_W = (size_t)HIDDEN * MLP_D;

    char* w = (char*)d_ws;
    const size_t SZ32 = (size_t)M_TOK * HIDDEN * 4;
    float* h        = (float*)w;  w += SZ32;
    float* attn_out = (float*)w;  w += SZ32;
    f16*   mid_h    = (f16*)w;    w += (size_t)M_PAD * MLP_D * 2;
    f16*   lnh1     = (f16*)w;    w += (size_t)M_PAD * HIDDEN * 2;
    f16*   lnh2     = (f16*)w;    w += (size_t)M_PAD * HIDDEN * 2;
    f16*   WmapT    = (f16*)w;    w += (size_t)768 * 768 * 2;
    f16*   qkvT     = (f16*)w;    w += (size_t)NBLOCKS * NHEADS * 3 * 64 * 64 * 2;
    size_t base_used = (size_t)(w - (char*)d_ws);
    bool big = ws_size >= base_used + 2 * NBLOCKS * LAYER_W * 2;
    f16* W1T = (f16*)w;  w += (big ? NBLOCKS : 1) * LAYER_W * 2;
    f16* W2T = (f16*)w;  w += (big ? NBLOCKS : 1) * LAYER_W * 2;

    f16* patches_h = mid_h;
    patchify_kernel<<<BATCH*NPATCH, 256, 0, stream>>>(x, patches_h);
    {
        dim3 g(12, 12, 1);
        transT_kernel<<<g, 256, 0, stream>>>(W_map, WmapT, 768, 768);
    }
    qkvtrans_kernel<<<NBLOCKS*NHEADS*3, 256, 0, stream>>>(Wq, Wk, Wv, qkvT);
    if (big) {
        dim3 g1(MLP_D/64, HIDDEN/64, NBLOCKS);
        transT_kernel<<<g1, 256, 0, stream>>>(W1, W1T, HIDDEN, MLP_D);
        dim3 g2(HIDDEN/64, MLP_D/64, NBLOCKS);
        transT_kernel<<<g2, 256, 0, stream>>>(W2, W2T, MLP_D, HIDDEN);
    }
    // tokens = patches @ W_map + b_map -> attn_out; M=6272=49*128 exact
    hgemm_kernel<0,64><<<49*12, 256, 0, stream>>>(patches_h, WmapT, b_map,
                                                  nullptr, nullptr,
                                                  (void*)attn_out, BATCH*NPATCH, 768, 768, 12);
    assemble_kernel<<<M_TOK, 256, 0, stream>>>(attn_out, cls_t, pos, h);

    for (int blk = 0; blk < NBLOCKS; ++blk) {
        f16* w1t = big ? (W1T + (size_t)blk * LAYER_W) : W1T;
        f16* w2t = big ? (W2T + (size_t)blk * LAYER_W) : W2T;
        layernorm2_kernel<<<M_TOK/4, 256, 0, stream>>>(h,
            ln1_s + blk*768, ln1_b + blk*768, ln2_s + blk*768, ln2_b + blk*768,
            lnh1, lnh2);
        if (!big) {
            dim3 g(MLP_D/32, HIDDEN/32, 2);
            convtrans2_kernel<<<g, 256, 0, stream>>>(W1 + (size_t)blk*LAYER_W,
                                                     W2 + (size_t)blk*LAYER_W, w1t, w2t);
        }
        {
            dim3 g(BATCH, NHEADS);
            fused_attn_kernel<<<g, 512, 0, stream>>>(lnh1,
                qkvT + (size_t)blk*NHEADS*3*4096,
                bq + (size_t)blk*768, bk + (size_t)blk*768, bv + (size_t)blk*768,
                attn_out);
        }
        // mid = gelu(lnh2 @ W1 + b1): 256x128 pipelined, grid 25x24=600, 2 blocks/CU
        hgemm9b_kernel<<<25*24, 512, 0, stream>>>(lnh2, w1t, b1 + (size_t)blk*MLP_D,
                                                  mid_h, M_TOK, MLP_D, 768, 24);
        // h = h + attn_out + (mid @ W2 + b2): r12-validated 2-phase
        hgemm_kernel<0,64><<<50*12, 256, 0, stream>>>(mid_h, w2t, b2 + (size_t)blk*HIDDEN,
                                                      h, attn_out,
                                                      (void*)h, M_TOK, HIDDEN, MLP_D, 12);
    }

    head_kernel<<<BATCH, 256, 0, stream>>>(h, W_out, b_out, out);
}

// Round 17
// 2341.184 us; speedup vs baseline: 1.0574x; 1.0574x over previous
//
#include <hip/hip_runtime.h>
#include <math.h>

#define BATCH   32
#define SEQ     197
#define HIDDEN  768
#define NHEADS  12
#define DHEAD   64
#define NBLOCKS 12
#define MLP_D   3072
#define OUTD    1000
#define NPATCH  196
#define M_TOK   (BATCH*SEQ)      // 6304
#define M_PAD   6400             // padded rows for fp16 activation buffers
#define LN_EPS  1e-5f
#define SP      208              // padded seq (13*16)

typedef _Float16 f16;
typedef _Float16 f16x8 __attribute__((ext_vector_type(8)));
typedef _Float16 f16x4 __attribute__((ext_vector_type(4)));
typedef float    f32x4 __attribute__((ext_vector_type(4)));

__device__ __forceinline__ float gelu_exact(float x) {
    return 0.5f * x * (1.0f + erff(x * 0.70710678118654752f));
}

__device__ __forceinline__ void gload_lds16(const void* g, void* l) {
    __builtin_amdgcn_global_load_lds(
        (const __attribute__((address_space(1))) void*)g,
        (__attribute__((address_space(3))) void*)l, 16, 0, 0);
}

// swizzled LDS read for 128B-stride rows (8 slots): slot XOR (row&7) — bijective
__device__ __forceinline__ f16x8 lds_ld(const char* base, int row, int rs, int kbyte) {
    return *(const f16x8*)(base + row*rs + (kbyte ^ ((row & 7) << 4)));
}

// BK=32 packed layout: physical row p (128B, 8 slots) holds logical rows 2p (slots 0-3)
// and 2p+1 (slots 4-7), slots XOR'd by (p&7). Fragment read: logical row r, k-chunk lg.
__device__ __forceinline__ f16x8 lds32(const char* buf, int row, int lg) {
    int p = row >> 1;
    int sl = (((row & 1) << 2) + lg) ^ (p & 7);
    return *(const f16x8*)(buf + p*128 + sl*16);
}

// ---------- patchify ----------
__global__ __launch_bounds__(256) void patchify_kernel(const float* __restrict__ x,
                                                       f16* __restrict__ patches) {
    int row = blockIdx.x;
    int n = row / NPATCH;
    int p = row % NPATCH;
    int pi = p / 14, pj = p % 14;
    for (int k = threadIdx.x; k < 768; k += 256) {
        int c   = k >> 8;
        int r   = (k >> 4) & 15;
        int col = k & 15;
        patches[(size_t)row*768 + k] =
            (f16)x[(((size_t)n*3 + c)*224 + (pi*16 + r))*224 + pj*16 + col];
    }
}

// ---------- batched fp32 [R][C] -> f16 transposed [C][R], 64x64 tiles, z = layer ----------
__global__ __launch_bounds__(256) void transT_kernel(const float* __restrict__ src,
                                                     f16* __restrict__ dst,
                                                     int R, int C) {
    const float* in = src + (size_t)blockIdx.z * R * C;
    f16* out = dst + (size_t)blockIdx.z * R * C;
    __shared__ float tile[64][65];
    int r0 = blockIdx.y * 64, c0 = blockIdx.x * 64;
    int t = threadIdx.x;
    int lr16 = t >> 4, lc4 = (t & 15) * 4;
    #pragma unroll
    for (int i = 0; i < 4; ++i) {
        int r = i*16 + lr16;
        float4 v = *(const float4*)&in[(size_t)(r0 + r)*C + c0 + lc4];
        tile[r][lc4] = v.x; tile[r][lc4+1] = v.y; tile[r][lc4+2] = v.z; tile[r][lc4+3] = v.w;
    }
    __syncthreads();
    #pragma unroll
    for (int i = 0; i < 4; ++i) {
        int c = i*16 + lr16;
        int r = lc4;
        f16x4 pv = { (f16)tile[r][c], (f16)tile[r+1][c], (f16)tile[r+2][c], (f16)tile[r+3][c] };
        *(f16x4*)&out[(size_t)(c0 + c)*R + r0 + r] = pv;
    }
}

// ---------- dual transpose (fallback path) ----------
__global__ __launch_bounds__(256) void convtrans2_kernel(const float* __restrict__ W1,
                                                         const float* __restrict__ W2,
                                                         f16* __restrict__ W1T,
                                                         f16* __restrict__ W2T) {
    int z = blockIdx.z;
    const float* in = z ? W2 : W1;
    f16* out = z ? W2T : W1T;
    int R = z ? MLP_D : HIDDEN;
    int C = z ? HIDDEN : MLP_D;
    int bx = z ? blockIdx.y : blockIdx.x;
    int by = z ? blockIdx.x : blockIdx.y;
    __shared__ float tile[32][33];
    int r0 = by * 32, c0 = bx * 32;
    int tx = threadIdx.x & 31, ty = threadIdx.x >> 5;
    #pragma unroll
    for (int i = 0; i < 4; ++i) {
        int r = ty + i*8;
        tile[r][tx] = in[(size_t)(r0 + r)*C + c0 + tx];
    }
    __syncthreads();
    #pragma unroll
    for (int i = 0; i < 4; ++i) {
        int r = ty + i*8;
        out[(size_t)(c0 + r)*R + r0 + tx] = (f16)tile[tx][r];
    }
}

// ---------- QKV weight transpose ----------
__global__ __launch_bounds__(256) void qkvtrans_kernel(const float* __restrict__ Wq,
                                                       const float* __restrict__ Wk,
                                                       const float* __restrict__ Wv,
                                                       f16* __restrict__ outT) {
    int b = blockIdx.x;
    int blkL = b / 36, rem = b % 36;
    int hh = rem / 3, mat = rem % 3;
    const float* in = (mat == 0 ? Wq : mat == 1 ? Wk : Wv) + ((size_t)(blkL*12 + hh))*4096;
    f16* out = outT + (size_t)b * 4096;
    __shared__ float tile[64][65];
    int t = threadIdx.x;
    for (int i = t; i < 4096; i += 256) tile[i >> 6][i & 63] = in[i];
    __syncthreads();
    for (int i = t; i < 4096; i += 256) out[i] = (f16)tile[i & 63][i >> 6];
}

// ---------- assemble ----------
__global__ __launch_bounds__(256) void assemble_kernel(const float* __restrict__ tokens,
                                                       const float* __restrict__ cls,
                                                       const float* __restrict__ pos,
                                                       float* __restrict__ h) {
    int r = blockIdx.x;
    int n = r / SEQ, s = r % SEQ;
    for (int c = threadIdx.x; c < 768; c += 256) {
        float v = (s == 0) ? cls[c] : tokens[(size_t)(n*NPATCH + s - 1)*768 + c];
        h[(size_t)r*768 + c] = v + pos[s*768 + c];
    }
}

// ---------- dual layernorm v2 (validated round 12) ----------
__global__ __launch_bounds__(256) void layernorm2_kernel(const float* __restrict__ x,
                                                         const float* __restrict__ s1,
                                                         const float* __restrict__ b1,
                                                         const float* __restrict__ s2,
                                                         const float* __restrict__ b2,
                                                         f16* __restrict__ o1,
                                                         f16* __restrict__ o2) {
    int wid = threadIdx.x >> 6, lane = threadIdx.x & 63;
    int r = blockIdx.x * 4 + wid;             // M_TOK = 1576*4 exact
    const float4* xr = (const float4*)(x + (size_t)r * 768);
    float4 v[3];
    v[0] = xr[lane]; v[1] = xr[lane + 64]; v[2] = xr[lane + 128];
    float s = v[0].x+v[0].y+v[0].z+v[0].w + v[1].x+v[1].y+v[1].z+v[1].w
            + v[2].x+v[2].y+v[2].z+v[2].w;
    #pragma unroll
    for (int off = 32; off > 0; off >>= 1) s += __shfl_xor(s, off);
    float mean = s * (1.0f/768.0f);
    float q = 0.f;
    #pragma unroll
    for (int j = 0; j < 3; ++j) {
        float a = v[j].x-mean, b = v[j].y-mean, c = v[j].z-mean, d = v[j].w-mean;
        q += a*a + b*b + c*c + d*d;
    }
    #pragma unroll
    for (int off = 32; off > 0; off >>= 1) q += __shfl_xor(q, off);
    float inv = rsqrtf(q * (1.0f/768.0f) + LN_EPS);
    #pragma unroll
    for (int j = 0; j < 3; ++j) {
        int col = (lane + 64*j) * 4;
        float4 sc1 = *(const float4*)(s1 + col);
        float4 bb1 = *(const float4*)(b1 + col);
        float4 sc2 = *(const float4*)(s2 + col);
        float4 bb2 = *(const float4*)(b2 + col);
        float a = (v[j].x-mean)*inv, b = (v[j].y-mean)*inv,
              c = (v[j].z-mean)*inv, d = (v[j].w-mean)*inv;
        f16x4 w1 = { (f16)(a*sc1.x+bb1.x), (f16)(b*sc1.y+bb1.y),
                     (f16)(c*sc1.z+bb1.z), (f16)(d*sc1.w+bb1.w) };
        f16x4 w2 = { (f16)(a*sc2.x+bb2.x), (f16)(b*sc2.y+bb2.y),
                     (f16)(c*sc2.z+bb2.z), (f16)(d*sc2.w+bb2.w) };
        *(f16x4*)(o1 + (size_t)r*768 + col) = w1;
        *(f16x4*)(o2 + (size_t)r*768 + col) = w2;
    }
}

// ---------- fused QKV + attention v2 (validated round 12) ----------
__global__ __launch_bounds__(512) void fused_attn_kernel(
        const f16* __restrict__ lnh, const f16* __restrict__ qkvT,
        const float* __restrict__ bq, const float* __restrict__ bk,
        const float* __restrict__ bv, float* __restrict__ O) {
    int n = blockIdx.x, h = blockIdx.y;
    int t = threadIdx.x, wid = t >> 6, lane = t & 63;
    int lr = lane & 15;
    int lg = lane >> 4;

    __shared__ char lds[153600];
    char* Xs  = lds;
    char* Qs  = lds + 26624;
    char* Ks  = lds + 53248;
    char* VsT = lds + 79872;
    char* Ws  = lds + 112640;
    char* Ps  = (wid < 3) ? (lds + wid*8192)
              : (wid < 6) ? (lds + 112640 + (wid-3)*8192)
                          : (lds + 137216 + (wid-6)*8192);

    const char* xsrc = (const char*)(lnh + (size_t)n*SEQ*768 + h*64);
    for (int c = t; c < SP*8; c += 512) {
        int s = c >> 3, kb = (c & 7) * 16;
        f16x8 v = {};
        if (s < SEQ) v = *(const f16x8*)(xsrc + (size_t)s*1536 + kb);
        *(f16x8*)(Xs + s*128 + (kb ^ ((s & 7) << 4))) = v;
    }
    const char* wsrc = (const char*)(qkvT) + (size_t)h * 3 * 4096 * 2;
    for (int c = t; c < 1536; c += 512) {
        int byte = c * 16, row = byte >> 7, kb = byte & 127;
        f16x8 v = *(const f16x8*)(wsrc + byte);
        *(f16x8*)(Ws + row*128 + (kb ^ ((row & 7) << 4))) = v;
    }
    for (int c = t; c < 384; c += 512) {
        int e = c / 6, sl = c % 6;
        int kb = 416 + sl * 16;
        *(f16x8*)(VsT + e*512 + (kb ^ ((e & 7) << 4))) = (f16x8){};
    }
    __syncthreads();

    for (int idx = wid; idx < 39; idx += 8) {
        int mat = idx / 13, mt = idx % 13;
        const float* bias = (mat == 0) ? bq : (mat == 1) ? bk : bv;
        #pragma unroll
        for (int nt = 0; nt < 4; ++nt) {
            f32x4 acc = {};
            #pragma unroll
            for (int ks = 0; ks < 2; ++ks) {
                f16x8 a = lds_ld(Xs, mt*16 + lr, 128, lg*16 + ks*64);
                f16x8 b = lds_ld(Ws, mat*64 + nt*16 + lr, 128, lg*16 + ks*64);
                acc = __builtin_amdgcn_mfma_f32_16x16x32_f16(a, b, acc, 0, 0, 0);
            }
            float bb = bias[h*64 + nt*16 + lr];
            if (mat < 2) {
                char* dst = (mat == 0) ? Qs : Ks;
                #pragma unroll
                for (int j = 0; j < 4; ++j) {
                    int s = mt*16 + lg*4 + j;
                    int eb = (nt*16 + lr) * 2;
                    *(f16*)(dst + s*128 + (eb ^ ((s & 7) << 4))) = (f16)(acc[j] + bb);
                }
            } else {
                int e = nt*16 + lr;
                int sb = (mt*16 + lg*4) * 2;
                f16x4 pv;
                #pragma unroll
                for (int j = 0; j < 4; ++j) pv[j] = (f16)(acc[j] + bb);
                *(f16x4*)(VsT + e*512 + (sb ^ ((e & 7) << 4))) = pv;
            }
        }
    }
    __syncthreads();

    for (int c = lane; c < 96; c += 64) {
        int r = c / 6, kb = 416 + (c % 6) * 16;
        *(f16x8*)(Ps + r*512 + (kb ^ ((r & 7) << 4))) = (f16x8){};
    }

    const float scale = 0.28867513459481288f;   // 1/sqrt(12)
    for (int mt = wid; mt < 13; mt += 8) {
        f32x4 sacc[13];
        #pragma unroll
        for (int nt = 0; nt < 13; ++nt) sacc[nt] = (f32x4){};
        #pragma unroll
        for (int ks = 0; ks < 2; ++ks) {
            f16x8 a = lds_ld(Qs, mt*16 + lr, 128, lg*16 + ks*64);
            #pragma unroll
            for (int nt = 0; nt < 13; ++nt) {
                f16x8 b = lds_ld(Ks, nt*16 + lr, 128, lg*16 + ks*64);
                sacc[nt] = __builtin_amdgcn_mfma_f32_16x16x32_f16(a, b, sacc[nt], 0, 0, 0);
            }
        }
        float mx0 = -1e30f, mx1 = -1e30f, mx2 = -1e30f, mx3 = -1e30f;
        #pragma unroll
        for (int nt = 0; nt < 13; ++nt) {
            bool valid = (nt*16 + lr) < SEQ;
            #pragma unroll
            for (int j = 0; j < 4; ++j) {
                float v = valid ? sacc[nt][j] * scale : -1e30f;
                sacc[nt][j] = v;
            }
            mx0 = fmaxf(mx0, sacc[nt][0]); mx1 = fmaxf(mx1, sacc[nt][1]);
            mx2 = fmaxf(mx2, sacc[nt][2]); mx3 = fmaxf(mx3, sacc[nt][3]);
        }
        #pragma unroll
        for (int off = 1; off < 16; off <<= 1) {
            mx0 = fmaxf(mx0, __shfl_xor(mx0, off));
            mx1 = fmaxf(mx1, __shfl_xor(mx1, off));
            mx2 = fmaxf(mx2, __shfl_xor(mx2, off));
            mx3 = fmaxf(mx3, __shfl_xor(mx3, off));
        }
        float s0 = 0.f, s1 = 0.f, s2 = 0.f, s3 = 0.f;
        #pragma unroll
        for (int nt = 0; nt < 13; ++nt) {
            float p0 = expf(sacc[nt][0] - mx0); sacc[nt][0] = p0; s0 += p0;
            float p1 = expf(sacc[nt][1] - mx1); sacc[nt][1] = p1; s1 += p1;
            float p2 = expf(sacc[nt][2] - mx2); sacc[nt][2] = p2; s2 += p2;
            float p3 = expf(sacc[nt][3] - mx3); sacc[nt][3] = p3; s3 += p3;
        }
        #pragma unroll
        for (int off = 1; off < 16; off <<= 1) {
            s0 += __shfl_xor(s0, off); s1 += __shfl_xor(s1, off);
            s2 += __shfl_xor(s2, off); s3 += __shfl_xor(s3, off);
        }
        float i0 = 1.0f/s0, i1 = 1.0f/s1, i2 = 1.0f/s2, i3 = 1.0f/s3;
        #pragma unroll
        for (int nt = 0; nt < 13; ++nt) {
            int cb = (nt*16 + lr) * 2;
            { int r = lg*4 + 0; *(f16*)(Ps + r*512 + (cb ^ ((r & 7) << 4))) = (f16)(sacc[nt][0] * i0); }
            { int r = lg*4 + 1; *(f16*)(Ps + r*512 + (cb ^ ((r & 7) << 4))) = (f16)(sacc[nt][1] * i1); }
            { int r = lg*4 + 2; *(f16*)(Ps + r*512 + (cb ^ ((r & 7) << 4))) = (f16)(sacc[nt][2] * i2); }
            { int r = lg*4 + 3; *(f16*)(Ps + r*512 + (cb ^ ((r & 7) << 4))) = (f16)(sacc[nt][3] * i3); }
        }
        f32x4 oacc[4] = {};
        #pragma unroll
        for (int ks = 0; ks < 8; ++ks) {
            f16x8 a = lds_ld(Ps, lr, 512, lg*16 + ks*64);
            #pragma unroll
            for (int nt = 0; nt < 4; ++nt) {
                f16x8 b = lds_ld(VsT, nt*16 + lr, 512, lg*16 + ks*64);
                oacc[nt] = __builtin_amdgcn_mfma_f32_16x16x32_f16(a, b, oacc[nt], 0, 0, 0);
            }
        }
        #pragma unroll
        for (int nt = 0; nt < 4; ++nt) {
            #pragma unroll
            for (int j = 0; j < 4; ++j) {
                int s = mt*16 + lg*4 + j;
                if (s < SEQ)
                    O[((size_t)(n*SEQ + s))*768 + h*64 + nt*16 + lr] = oacc[nt][j];
            }
        }
    }
}

// ---------- fp16 MFMA GEMM (round-12 validated): TM=128, TN=64, BK=32, 24 KB LDS ----------
template<int MODE, int TN>
__global__ __launch_bounds__(256) void hgemm_kernel(
        const f16* __restrict__ A, const f16* __restrict__ BT,
        const float* __restrict__ bias,
        const float* __restrict__ res1, const float* __restrict__ res2,
        void* __restrict__ Cout, int M, int N, int K, int nbx) {
    constexpr int BISS = TN / 64;
    constexpr int WN   = TN / 2;
    constexpr int NFR  = WN / 16;
    __shared__ f16 As[2][128*32];
    __shared__ f16 Bs[2][TN*32];
    int t = threadIdx.x;
    int wid = t >> 6, lane = t & 63;
    int lr = lane & 15, lg = lane >> 4;
    int wr = wid >> 1, wc = wid & 1;

    int nwg = gridDim.x, bid = blockIdx.x;
    int q = nwg >> 3, r = nwg & 7;
    int xcd = bid & 7, idx = bid >> 3;
    int swz = (xcd < r) ? xcd*(q+1) + idx : r*(q+1) + (xcd-r)*q + idx;
    int bn = (swz % nbx) * TN;
    int bm = (swz / nbx) * 128;

    int agrow[2], agk[2], bgrow[BISS], bgk[BISS];
    #pragma unroll
    for (int i = 0; i < 2; ++i) {
        int fb = i*4096 + wid*1024 + lane*16;
        int p = fb >> 7, u = ((fb >> 4) & 7) ^ (p & 7);
        agrow[i] = 2*p + (u >> 2); agk[i] = (u & 3) * 8;
    }
    #pragma unroll
    for (int i = 0; i < BISS; ++i) {
        int fb = i*4096 + wid*1024 + lane*16;
        int p = fb >> 7, u = ((fb >> 4) & 7) ^ (p & 7);
        bgrow[i] = 2*p + (u >> 2); bgk[i] = (u & 3) * 8;
    }

    #define STAGE(P, K0)                                                          \
        do {                                                                      \
            _Pragma("unroll")                                                     \
            for (int i = 0; i < 2; ++i)                                           \
                gload_lds16(A + (size_t)(bm + agrow[i])*K + (K0) + agk[i],        \
                            (char*)&As[P][0] + i*4096 + wid*1024);                \
            _Pragma("unroll")                                                     \
            for (int i = 0; i < BISS; ++i)                                        \
                gload_lds16(BT + (size_t)(bn + bgrow[i])*K + (K0) + bgk[i],       \
                            (char*)&Bs[P][0] + i*4096 + wid*1024);                \
        } while (0)

    f32x4 acc[4][NFR] = {};
    int nk = K >> 5;

    STAGE(0, 0);
    __syncthreads();
    for (int kt = 0; kt < nk; ++kt) {
        int cur = kt & 1;
        if (kt + 1 < nk) STAGE(cur ^ 1, (kt + 1) * 32);
        const char* Ab = (const char*)&As[cur][0];
        const char* Bb = (const char*)&Bs[cur][0];
        f16x8 a[4], b[NFR];
        #pragma unroll
        for (int m = 0; m < 4; ++m)
            a[m] = lds32(Ab, wr*64 + m*16 + lr, lg);
        #pragma unroll
        for (int nn = 0; nn < NFR; ++nn)
            b[nn] = lds32(Bb, wc*WN + nn*16 + lr, lg);
        #pragma unroll
        for (int m = 0; m < 4; ++m)
            #pragma unroll
            for (int nn = 0; nn < NFR; ++nn)
                acc[m][nn] = __builtin_amdgcn_mfma_f32_16x16x32_f16(a[m], b[nn], acc[m][nn], 0, 0, 0);
        __syncthreads();
    }
    #undef STAGE

    int row0 = bm + wr*64 + lg*4;
    int col0 = bn + wc*WN + lr;
    #pragma unroll
    for (int m = 0; m < 4; ++m) {
        #pragma unroll
        for (int nn = 0; nn < NFR; ++nn) {
            int col = col0 + nn*16;
            float bv = bias[col];
            #pragma unroll
            for (int j = 0; j < 4; ++j) {
                int row = row0 + m*16 + j;
                if (row >= M) continue;
                float v = acc[m][nn][j] + bv;
                size_t idx = (size_t)row*N + col;
                if (MODE == 0) {
                    if (res1) v += res1[idx] + res2[idx];
                    ((float*)Cout)[idx] = v;
                } else {
                    ((f16*)Cout)[idx] = (f16)gelu_exact(v);
                }
            }
        }
    }
}

// ---------- fused classifier head ----------
__global__ __launch_bounds__(256) void head_kernel(const float* __restrict__ h,
                                                   const float* __restrict__ W_out,
                                                   const float* __restrict__ b_out,
                                                   float* __restrict__ out) {
    int n = blockIdx.x, t = threadIdx.x;
    __shared__ float xs[HIDDEN];
    __shared__ float red[4];
    const float* hr = h + (size_t)n*SEQ*HIDDEN;
    for (int k = t; k < HIDDEN; k += 256) xs[k] = hr[k];
    __syncthreads();

    bool v3 = t < (OUTD - 768);
    int c3 = v3 ? (t + 768) : t;
    float a0 = 0.f, a1 = 0.f, a2 = 0.f, a3 = 0.f;
    #pragma unroll 8
    for (int k = 0; k < HIDDEN; ++k) {
        float xv = xs[k];
        const float* wr = W_out + (size_t)k*OUTD;
        a0 = fmaf(xv, wr[t],       a0);
        a1 = fmaf(xv, wr[t + 256], a1);
        a2 = fmaf(xv, wr[t + 512], a2);
        a3 = fmaf(xv, wr[c3],      a3);
    }
    a0 += b_out[t]; a1 += b_out[t + 256]; a2 += b_out[t + 512];
    a3 = v3 ? (a3 + b_out[t + 768]) : -1e30f;

    int wid = t >> 6, lane = t & 63;
    float mx = fmaxf(fmaxf(a0, a1), fmaxf(a2, a3));
    #pragma unroll
    for (int off = 32; off > 0; off >>= 1) mx = fmaxf(mx, __shfl_xor(mx, off));
    if (lane == 0) red[wid] = mx;
    __syncthreads();
    mx = fmaxf(fmaxf(red[0], red[1]), fmaxf(red[2], red[3]));
    __syncthreads();

    float p0 = expf(a0 - mx), p1 = expf(a1 - mx), p2 = expf(a2 - mx);
    float p3 = v3 ? expf(a3 - mx) : 0.f;
    float s = p0 + p1 + p2 + p3;
    #pragma unroll
    for (int off = 32; off > 0; off >>= 1) s += __shfl_xor(s, off);
    if (lane == 0) red[wid] = s;
    __syncthreads();
    s = red[0] + red[1] + red[2] + red[3];
    float inv = 1.0f / s;

    float* orow = out + (size_t)n*OUTD;
    orow[t]       = p0 * inv;
    orow[t + 256] = p1 * inv;
    orow[t + 512] = p2 * inv;
    if (v3) orow[t + 768] = p3 * inv;
}

extern "C" void kernel_launch(void* const* d_in, const int* in_sizes, int n_in,
                              void* d_out, int out_size, void* d_ws, size_t ws_size,
                              hipStream_t stream) {
    const float* x     = (const float*)d_in[0];
    const float* W_map = (const float*)d_in[1];
    const float* b_map = (const float*)d_in[2];
    const float* cls_t = (const float*)d_in[3];
    const float* pos   = (const float*)d_in[4];
    const float* ln1_s = (const float*)d_in[5];
    const float* ln1_b = (const float*)d_in[6];
    const float* Wq    = (const float*)d_in[7];
    const float* bq    = (const float*)d_in[8];
    const float* Wk    = (const float*)d_in[9];
    const float* bk    = (const float*)d_in[10];
    const float* Wv    = (const float*)d_in[11];
    const float* bv    = (const float*)d_in[12];
    const float* ln2_s = (const float*)d_in[13];
    const float* ln2_b = (const float*)d_in[14];
    const float* W1    = (const float*)d_in[15];
    const float* b1    = (const float*)d_in[16];
    const float* W2    = (const float*)d_in[17];
    const float* b2    = (const float*)d_in[18];
    const float* W_out = (const float*)d_in[19];
    const float* b_out = (const float*)d_in[20];
    float* out = (float*)d_out;

    const size_t LAYER_W = (size_t)HIDDEN * MLP_D;

    char* w = (char*)d_ws;
    const size_t SZ32 = (size_t)M_TOK * HIDDEN * 4;
    float* h        = (float*)w;  w += SZ32;
    float* attn_out = (float*)w;  w += SZ32;
    f16*   mid_h    = (f16*)w;    w += (size_t)M_PAD * MLP_D * 2;
    f16*   lnh1     = (f16*)w;    w += (size_t)M_PAD * HIDDEN * 2;
    f16*   lnh2     = (f16*)w;    w += (size_t)M_PAD * HIDDEN * 2;
    f16*   WmapT    = (f16*)w;    w += (size_t)768 * 768 * 2;
    f16*   qkvT     = (f16*)w;    w += (size_t)NBLOCKS * NHEADS * 3 * 64 * 64 * 2;
    size_t base_used = (size_t)(w - (char*)d_ws);
    bool big = ws_size >= base_used + 2 * NBLOCKS * LAYER_W * 2;
    f16* W1T = (f16*)w;  w += (big ? NBLOCKS : 1) * LAYER_W * 2;
    f16* W2T = (f16*)w;  w += (big ? NBLOCKS : 1) * LAYER_W * 2;

    f16* patches_h = mid_h;
    patchify_kernel<<<BATCH*NPATCH, 256, 0, stream>>>(x, patches_h);
    {
        dim3 g(12, 12, 1);
        transT_kernel<<<g, 256, 0, stream>>>(W_map, WmapT, 768, 768);
    }
    qkvtrans_kernel<<<NBLOCKS*NHEADS*3, 256, 0, stream>>>(Wq, Wk, Wv, qkvT);
    if (big) {
        dim3 g1(MLP_D/64, HIDDEN/64, NBLOCKS);
        transT_kernel<<<g1, 256, 0, stream>>>(W1, W1T, HIDDEN, MLP_D);
        dim3 g2(HIDDEN/64, MLP_D/64, NBLOCKS);
        transT_kernel<<<g2, 256, 0, stream>>>(W2, W2T, MLP_D, HIDDEN);
    }
    // tokens = patches @ W_map + b_map -> attn_out; M=6272=49*128 exact
    hgemm_kernel<0,64><<<49*12, 256, 0, stream>>>(patches_h, WmapT, b_map,
                                                  nullptr, nullptr,
                                                  (void*)attn_out, BATCH*NPATCH, 768, 768, 12);
    assemble_kernel<<<M_TOK, 256, 0, stream>>>(attn_out, cls_t, pos, h);

    for (int blk = 0; blk < NBLOCKS; ++blk) {
        f16* w1t = big ? (W1T + (size_t)blk * LAYER_W) : W1T;
        f16* w2t = big ? (W2T + (size_t)blk * LAYER_W) : W2T;
        layernorm2_kernel<<<M_TOK/4, 256, 0, stream>>>(h,
            ln1_s + blk*768, ln1_b + blk*768, ln2_s + blk*768, ln2_b + blk*768,
            lnh1, lnh2);
        if (!big) {
            dim3 g(MLP_D/32, HIDDEN/32, 2);
            convtrans2_kernel<<<g, 256, 0, stream>>>(W1 + (size_t)blk*LAYER_W,
                                                     W2 + (size_t)blk*LAYER_W, w1t, w2t);
        }
        {
            dim3 g(BATCH, NHEADS);
            fused_attn_kernel<<<g, 512, 0, stream>>>(lnh1,
                qkvT + (size_t)blk*NHEADS*3*4096,
                bq + (size_t)blk*768, bk + (size_t)blk*768, bv + (size_t)blk*768,
                attn_out);
        }
        // mid = gelu(lnh2 @ W1 + b1), N=3072: grid 50x48 (round-12 best)
        hgemm_kernel<1,64><<<50*48, 256, 0, stream>>>(lnh2, w1t, b1 + (size_t)blk*MLP_D,
                                                      nullptr, nullptr,
                                                      (void*)mid_h, M_TOK, MLP_D, 768, 48);
        // h = h + attn_out + (mid @ W2 + b2), N=768: grid 50x12
        hgemm_kernel<0,64><<<50*12, 256, 0, stream>>>(mid_h, w2t, b2 + (size_t)blk*HIDDEN,
                                                      h, attn_out,
                                                      (void*)h, M_TOK, HIDDEN, MLP_D, 12);
    }

    head_kernel<<<BATCH, 256, 0, stream>>>(h, W_out, b_out, out);
}

// Round 18
// 2335.409 us; speedup vs baseline: 1.0600x; 1.0025x over previous
//
#include <hip/hip_runtime.h>
#include <math.h>

#define BATCH   32
#define SEQ     197
#define HIDDEN  768
#define NHEADS  12
#define DHEAD   64
#define NBLOCKS 12
#define MLP_D   3072
#define OUTD    1000
#define NPATCH  196
#define M_TOK   (BATCH*SEQ)      // 6304
#define M_PAD   6400             // padded rows for fp16 activation buffers
#define LN_EPS  1e-5f
#define SP      208              // padded seq (13*16)

typedef _Float16 f16;
typedef _Float16 f16x8 __attribute__((ext_vector_type(8)));
typedef _Float16 f16x4 __attribute__((ext_vector_type(4)));
typedef float    f32x4 __attribute__((ext_vector_type(4)));

__device__ __forceinline__ float gelu_exact(float x) {
    return 0.5f * x * (1.0f + erff(x * 0.70710678118654752f));
}

__device__ __forceinline__ void gload_lds16(const void* g, void* l) {
    __builtin_amdgcn_global_load_lds(
        (const __attribute__((address_space(1))) void*)g,
        (__attribute__((address_space(3))) void*)l, 16, 0, 0);
}

// swizzled LDS read for 128B-stride rows (8 slots): slot XOR (row&7) — bijective
__device__ __forceinline__ f16x8 lds_ld(const char* base, int row, int rs, int kbyte) {
    return *(const f16x8*)(base + row*rs + (kbyte ^ ((row & 7) << 4)));
}

// BK=32 packed layout: physical row p (128B, 8 slots) holds logical rows 2p (slots 0-3)
// and 2p+1 (slots 4-7), slots XOR'd by (p&7). Fragment read: logical row r, k-chunk lg.
__device__ __forceinline__ f16x8 lds32(const char* buf, int row, int lg) {
    int p = row >> 1;
    int sl = (((row & 1) << 2) + lg) ^ (p & 7);
    return *(const f16x8*)(buf + p*128 + sl*16);
}

// ---------- patchify ----------
__global__ __launch_bounds__(256) void patchify_kernel(const float* __restrict__ x,
                                                       f16* __restrict__ patches) {
    int row = blockIdx.x;
    int n = row / NPATCH;
    int p = row % NPATCH;
    int pi = p / 14, pj = p % 14;
    for (int k = threadIdx.x; k < 768; k += 256) {
        int c   = k >> 8;
        int r   = (k >> 4) & 15;
        int col = k & 15;
        patches[(size_t)row*768 + k] =
            (f16)x[(((size_t)n*3 + c)*224 + (pi*16 + r))*224 + pj*16 + col];
    }
}

// ---------- batched fp32 [R][C] -> f16 transposed [C][R], 64x64 tiles, z = layer ----------
__global__ __launch_bounds__(256) void transT_kernel(const float* __restrict__ src,
                                                     f16* __restrict__ dst,
                                                     int R, int C) {
    const float* in = src + (size_t)blockIdx.z * R * C;
    f16* out = dst + (size_t)blockIdx.z * R * C;
    __shared__ float tile[64][65];
    int r0 = blockIdx.y * 64, c0 = blockIdx.x * 64;
    int t = threadIdx.x;
    int lr16 = t >> 4, lc4 = (t & 15) * 4;
    #pragma unroll
    for (int i = 0; i < 4; ++i) {
        int r = i*16 + lr16;
        float4 v = *(const float4*)&in[(size_t)(r0 + r)*C + c0 + lc4];
        tile[r][lc4] = v.x; tile[r][lc4+1] = v.y; tile[r][lc4+2] = v.z; tile[r][lc4+3] = v.w;
    }
    __syncthreads();
    #pragma unroll
    for (int i = 0; i < 4; ++i) {
        int c = i*16 + lr16;
        int r = lc4;
        f16x4 pv = { (f16)tile[r][c], (f16)tile[r+1][c], (f16)tile[r+2][c], (f16)tile[r+3][c] };
        *(f16x4*)&out[(size_t)(c0 + c)*R + r0 + r] = pv;
    }
}

// ---------- dual transpose (fallback path) ----------
__global__ __launch_bounds__(256) void convtrans2_kernel(const float* __restrict__ W1,
                                                         const float* __restrict__ W2,
                                                         f16* __restrict__ W1T,
                                                         f16* __restrict__ W2T) {
    int z = blockIdx.z;
    const float* in = z ? W2 : W1;
    f16* out = z ? W2T : W1T;
    int R = z ? MLP_D : HIDDEN;
    int C = z ? HIDDEN : MLP_D;
    int bx = z ? blockIdx.y : blockIdx.x;
    int by = z ? blockIdx.x : blockIdx.y;
    __shared__ float tile[32][33];
    int r0 = by * 32, c0 = bx * 32;
    int tx = threadIdx.x & 31, ty = threadIdx.x >> 5;
    #pragma unroll
    for (int i = 0; i < 4; ++i) {
        int r = ty + i*8;
        tile[r][tx] = in[(size_t)(r0 + r)*C + c0 + tx];
    }
    __syncthreads();
    #pragma unroll
    for (int i = 0; i < 4; ++i) {
        int r = ty + i*8;
        out[(size_t)(c0 + r)*R + r0 + tx] = (f16)tile[tx][r];
    }
}

// ---------- QKV weight transpose ----------
__global__ __launch_bounds__(256) void qkvtrans_kernel(const float* __restrict__ Wq,
                                                       const float* __restrict__ Wk,
                                                       const float* __restrict__ Wv,
                                                       f16* __restrict__ outT) {
    int b = blockIdx.x;
    int blkL = b / 36, rem = b % 36;
    int hh = rem / 3, mat = rem % 3;
    const float* in = (mat == 0 ? Wq : mat == 1 ? Wk : Wv) + ((size_t)(blkL*12 + hh))*4096;
    f16* out = outT + (size_t)b * 4096;
    __shared__ float tile[64][65];
    int t = threadIdx.x;
    for (int i = t; i < 4096; i += 256) tile[i >> 6][i & 63] = in[i];
    __syncthreads();
    for (int i = t; i < 4096; i += 256) out[i] = (f16)tile[i & 63][i >> 6];
}

// ---------- assemble ----------
__global__ __launch_bounds__(256) void assemble_kernel(const float* __restrict__ tokens,
                                                       const float* __restrict__ cls,
                                                       const float* __restrict__ pos,
                                                       float* __restrict__ h) {
    int r = blockIdx.x;
    int n = r / SEQ, s = r % SEQ;
    for (int c = threadIdx.x; c < 768; c += 256) {
        float v = (s == 0) ? cls[c] : tokens[(size_t)(n*NPATCH + s - 1)*768 + c];
        h[(size_t)r*768 + c] = v + pos[s*768 + c];
    }
}

// ---------- dual layernorm v2 (validated round 12) ----------
__global__ __launch_bounds__(256) void layernorm2_kernel(const float* __restrict__ x,
                                                         const float* __restrict__ s1,
                                                         const float* __restrict__ b1,
                                                         const float* __restrict__ s2,
                                                         const float* __restrict__ b2,
                                                         f16* __restrict__ o1,
                                                         f16* __restrict__ o2) {
    int wid = threadIdx.x >> 6, lane = threadIdx.x & 63;
    int r = blockIdx.x * 4 + wid;             // M_TOK = 1576*4 exact
    const float4* xr = (const float4*)(x + (size_t)r * 768);
    float4 v[3];
    v[0] = xr[lane]; v[1] = xr[lane + 64]; v[2] = xr[lane + 128];
    float s = v[0].x+v[0].y+v[0].z+v[0].w + v[1].x+v[1].y+v[1].z+v[1].w
            + v[2].x+v[2].y+v[2].z+v[2].w;
    #pragma unroll
    for (int off = 32; off > 0; off >>= 1) s += __shfl_xor(s, off);
    float mean = s * (1.0f/768.0f);
    float q = 0.f;
    #pragma unroll
    for (int j = 0; j < 3; ++j) {
        float a = v[j].x-mean, b = v[j].y-mean, c = v[j].z-mean, d = v[j].w-mean;
        q += a*a + b*b + c*c + d*d;
    }
    #pragma unroll
    for (int off = 32; off > 0; off >>= 1) q += __shfl_xor(q, off);
    float inv = rsqrtf(q * (1.0f/768.0f) + LN_EPS);
    #pragma unroll
    for (int j = 0; j < 3; ++j) {
        int col = (lane + 64*j) * 4;
        float4 sc1 = *(const float4*)(s1 + col);
        float4 bb1 = *(const float4*)(b1 + col);
        float4 sc2 = *(const float4*)(s2 + col);
        float4 bb2 = *(const float4*)(b2 + col);
        float a = (v[j].x-mean)*inv, b = (v[j].y-mean)*inv,
              c = (v[j].z-mean)*inv, d = (v[j].w-mean)*inv;
        f16x4 w1 = { (f16)(a*sc1.x+bb1.x), (f16)(b*sc1.y+bb1.y),
                     (f16)(c*sc1.z+bb1.z), (f16)(d*sc1.w+bb1.w) };
        f16x4 w2 = { (f16)(a*sc2.x+bb2.x), (f16)(b*sc2.y+bb2.y),
                     (f16)(c*sc2.z+bb2.z), (f16)(d*sc2.w+bb2.w) };
        *(f16x4*)(o1 + (size_t)r*768 + col) = w1;
        *(f16x4*)(o2 + (size_t)r*768 + col) = w2;
    }
}

// ---------- fused QKV + attention v2 (validated r12), output f16 ----------
__global__ __launch_bounds__(512) void fused_attn_kernel(
        const f16* __restrict__ lnh, const f16* __restrict__ qkvT,
        const float* __restrict__ bq, const float* __restrict__ bk,
        const float* __restrict__ bv, f16* __restrict__ O) {
    int n = blockIdx.x, h = blockIdx.y;
    int t = threadIdx.x, wid = t >> 6, lane = t & 63;
    int lr = lane & 15;
    int lg = lane >> 4;

    __shared__ char lds[153600];
    char* Xs  = lds;
    char* Qs  = lds + 26624;
    char* Ks  = lds + 53248;
    char* VsT = lds + 79872;
    char* Ws  = lds + 112640;
    char* Ps  = (wid < 3) ? (lds + wid*8192)
              : (wid < 6) ? (lds + 112640 + (wid-3)*8192)
                          : (lds + 137216 + (wid-6)*8192);

    const char* xsrc = (const char*)(lnh + (size_t)n*SEQ*768 + h*64);
    for (int c = t; c < SP*8; c += 512) {
        int s = c >> 3, kb = (c & 7) * 16;
        f16x8 v = {};
        if (s < SEQ) v = *(const f16x8*)(xsrc + (size_t)s*1536 + kb);
        *(f16x8*)(Xs + s*128 + (kb ^ ((s & 7) << 4))) = v;
    }
    const char* wsrc = (const char*)(qkvT) + (size_t)h * 3 * 4096 * 2;
    for (int c = t; c < 1536; c += 512) {
        int byte = c * 16, row = byte >> 7, kb = byte & 127;
        f16x8 v = *(const f16x8*)(wsrc + byte);
        *(f16x8*)(Ws + row*128 + (kb ^ ((row & 7) << 4))) = v;
    }
    for (int c = t; c < 384; c += 512) {
        int e = c / 6, sl = c % 6;
        int kb = 416 + sl * 16;
        *(f16x8*)(VsT + e*512 + (kb ^ ((e & 7) << 4))) = (f16x8){};
    }
    __syncthreads();

    for (int idx = wid; idx < 39; idx += 8) {
        int mat = idx / 13, mt = idx % 13;
        const float* bias = (mat == 0) ? bq : (mat == 1) ? bk : bv;
        #pragma unroll
        for (int nt = 0; nt < 4; ++nt) {
            f32x4 acc = {};
            #pragma unroll
            for (int ks = 0; ks < 2; ++ks) {
                f16x8 a = lds_ld(Xs, mt*16 + lr, 128, lg*16 + ks*64);
                f16x8 b = lds_ld(Ws, mat*64 + nt*16 + lr, 128, lg*16 + ks*64);
                acc = __builtin_amdgcn_mfma_f32_16x16x32_f16(a, b, acc, 0, 0, 0);
            }
            float bb = bias[h*64 + nt*16 + lr];
            if (mat < 2) {
                char* dst = (mat == 0) ? Qs : Ks;
                #pragma unroll
                for (int j = 0; j < 4; ++j) {
                    int s = mt*16 + lg*4 + j;
                    int eb = (nt*16 + lr) * 2;
                    *(f16*)(dst + s*128 + (eb ^ ((s & 7) << 4))) = (f16)(acc[j] + bb);
                }
            } else {
                int e = nt*16 + lr;
                int sb = (mt*16 + lg*4) * 2;
                f16x4 pv;
                #pragma unroll
                for (int j = 0; j < 4; ++j) pv[j] = (f16)(acc[j] + bb);
                *(f16x4*)(VsT + e*512 + (sb ^ ((e & 7) << 4))) = pv;
            }
        }
    }
    __syncthreads();

    for (int c = lane; c < 96; c += 64) {
        int r = c / 6, kb = 416 + (c % 6) * 16;
        *(f16x8*)(Ps + r*512 + (kb ^ ((r & 7) << 4))) = (f16x8){};
    }

    const float scale = 0.28867513459481288f;   // 1/sqrt(12)
    for (int mt = wid; mt < 13; mt += 8) {
        f32x4 sacc[13];
        #pragma unroll
        for (int nt = 0; nt < 13; ++nt) sacc[nt] = (f32x4){};
        #pragma unroll
        for (int ks = 0; ks < 2; ++ks) {
            f16x8 a = lds_ld(Qs, mt*16 + lr, 128, lg*16 + ks*64);
            #pragma unroll
            for (int nt = 0; nt < 13; ++nt) {
                f16x8 b = lds_ld(Ks, nt*16 + lr, 128, lg*16 + ks*64);
                sacc[nt] = __builtin_amdgcn_mfma_f32_16x16x32_f16(a, b, sacc[nt], 0, 0, 0);
            }
        }
        float mx0 = -1e30f, mx1 = -1e30f, mx2 = -1e30f, mx3 = -1e30f;
        #pragma unroll
        for (int nt = 0; nt < 13; ++nt) {
            bool valid = (nt*16 + lr) < SEQ;
            #pragma unroll
            for (int j = 0; j < 4; ++j) {
                float v = valid ? sacc[nt][j] * scale : -1e30f;
                sacc[nt][j] = v;
            }
            mx0 = fmaxf(mx0, sacc[nt][0]); mx1 = fmaxf(mx1, sacc[nt][1]);
            mx2 = fmaxf(mx2, sacc[nt][2]); mx3 = fmaxf(mx3, sacc[nt][3]);
        }
        #pragma unroll
        for (int off = 1; off < 16; off <<= 1) {
            mx0 = fmaxf(mx0, __shfl_xor(mx0, off));
            mx1 = fmaxf(mx1, __shfl_xor(mx1, off));
            mx2 = fmaxf(mx2, __shfl_xor(mx2, off));
            mx3 = fmaxf(mx3, __shfl_xor(mx3, off));
        }
        float s0 = 0.f, s1 = 0.f, s2 = 0.f, s3 = 0.f;
        #pragma unroll
        for (int nt = 0; nt < 13; ++nt) {
            float p0 = expf(sacc[nt][0] - mx0); sacc[nt][0] = p0; s0 += p0;
            float p1 = expf(sacc[nt][1] - mx1); sacc[nt][1] = p1; s1 += p1;
            float p2 = expf(sacc[nt][2] - mx2); sacc[nt][2] = p2; s2 += p2;
            float p3 = expf(sacc[nt][3] - mx3); sacc[nt][3] = p3; s3 += p3;
        }
        #pragma unroll
        for (int off = 1; off < 16; off <<= 1) {
            s0 += __shfl_xor(s0, off); s1 += __shfl_xor(s1, off);
            s2 += __shfl_xor(s2, off); s3 += __shfl_xor(s3, off);
        }
        float i0 = 1.0f/s0, i1 = 1.0f/s1, i2 = 1.0f/s2, i3 = 1.0f/s3;
        #pragma unroll
        for (int nt = 0; nt < 13; ++nt) {
            int cb = (nt*16 + lr) * 2;
            { int r = lg*4 + 0; *(f16*)(Ps + r*512 + (cb ^ ((r & 7) << 4))) = (f16)(sacc[nt][0] * i0); }
            { int r = lg*4 + 1; *(f16*)(Ps + r*512 + (cb ^ ((r & 7) << 4))) = (f16)(sacc[nt][1] * i1); }
            { int r = lg*4 + 2; *(f16*)(Ps + r*512 + (cb ^ ((r & 7) << 4))) = (f16)(sacc[nt][2] * i2); }
            { int r = lg*4 + 3; *(f16*)(Ps + r*512 + (cb ^ ((r & 7) << 4))) = (f16)(sacc[nt][3] * i3); }
        }
        f32x4 oacc[4] = {};
        #pragma unroll
        for (int ks = 0; ks < 8; ++ks) {
            f16x8 a = lds_ld(Ps, lr, 512, lg*16 + ks*64);
            #pragma unroll
            for (int nt = 0; nt < 4; ++nt) {
                f16x8 b = lds_ld(VsT, nt*16 + lr, 512, lg*16 + ks*64);
                oacc[nt] = __builtin_amdgcn_mfma_f32_16x16x32_f16(a, b, oacc[nt], 0, 0, 0);
            }
        }
        #pragma unroll
        for (int nt = 0; nt < 4; ++nt) {
            #pragma unroll
            for (int j = 0; j < 4; ++j) {
                int s = mt*16 + lg*4 + j;
                if (s < SEQ)
                    O[((size_t)(n*SEQ + s))*768 + h*64 + nt*16 + lr] = (f16)oacc[nt][j];
            }
        }
    }
}

// ---------- fp16 MFMA GEMM (round-12 validated): TM=128, TN=64, BK=32, 24 KB LDS ----------
// MODE 0: C fp32 = acc + bias (+ res1(f32) + res2(f16));  MODE 1: C f16 = gelu(acc+bias)
template<int MODE, int TN>
__global__ __launch_bounds__(256) void hgemm_kernel(
        const f16* __restrict__ A, const f16* __restrict__ BT,
        const float* __restrict__ bias,
        const float* __restrict__ res1, const f16* __restrict__ res2,
        void* __restrict__ Cout, int M, int N, int K, int nbx) {
    constexpr int BISS = TN / 64;
    constexpr int WN   = TN / 2;
    constexpr int NFR  = WN / 16;
    __shared__ f16 As[2][128*32];
    __shared__ f16 Bs[2][TN*32];
    int t = threadIdx.x;
    int wid = t >> 6, lane = t & 63;
    int lr = lane & 15, lg = lane >> 4;
    int wr = wid >> 1, wc = wid & 1;

    int nwg = gridDim.x, bid = blockIdx.x;
    int q = nwg >> 3, r = nwg & 7;
    int xcd = bid & 7, idx = bid >> 3;
    int swz = (xcd < r) ? xcd*(q+1) + idx : r*(q+1) + (xcd-r)*q + idx;
    int bn = (swz % nbx) * TN;
    int bm = (swz / nbx) * 128;

    int agrow[2], agk[2], bgrow[BISS], bgk[BISS];
    #pragma unroll
    for (int i = 0; i < 2; ++i) {
        int fb = i*4096 + wid*1024 + lane*16;
        int p = fb >> 7, u = ((fb >> 4) & 7) ^ (p & 7);
        agrow[i] = 2*p + (u >> 2); agk[i] = (u & 3) * 8;
    }
    #pragma unroll
    for (int i = 0; i < BISS; ++i) {
        int fb = i*4096 + wid*1024 + lane*16;
        int p = fb >> 7, u = ((fb >> 4) & 7) ^ (p & 7);
        bgrow[i] = 2*p + (u >> 2); bgk[i] = (u & 3) * 8;
    }

    #define STAGE(P, K0)                                                          \
        do {                                                                      \
            _Pragma("unroll")                                                     \
            for (int i = 0; i < 2; ++i)                                           \
                gload_lds16(A + (size_t)(bm + agrow[i])*K + (K0) + agk[i],        \
                            (char*)&As[P][0] + i*4096 + wid*1024);                \
            _Pragma("unroll")                                                     \
            for (int i = 0; i < BISS; ++i)                                        \
                gload_lds16(BT + (size_t)(bn + bgrow[i])*K + (K0) + bgk[i],       \
                            (char*)&Bs[P][0] + i*4096 + wid*1024);                \
        } while (0)

    f32x4 acc[4][NFR] = {};
    int nk = K >> 5;

    STAGE(0, 0);
    __syncthreads();
    for (int kt = 0; kt < nk; ++kt) {
        int cur = kt & 1;
        if (kt + 1 < nk) STAGE(cur ^ 1, (kt + 1) * 32);
        const char* Ab = (const char*)&As[cur][0];
        const char* Bb = (const char*)&Bs[cur][0];
        f16x8 a[4], b[NFR];
        #pragma unroll
        for (int m = 0; m < 4; ++m)
            a[m] = lds32(Ab, wr*64 + m*16 + lr, lg);
        #pragma unroll
        for (int nn = 0; nn < NFR; ++nn)
            b[nn] = lds32(Bb, wc*WN + nn*16 + lr, lg);
        #pragma unroll
        for (int m = 0; m < 4; ++m)
            #pragma unroll
            for (int nn = 0; nn < NFR; ++nn)
                acc[m][nn] = __builtin_amdgcn_mfma_f32_16x16x32_f16(a[m], b[nn], acc[m][nn], 0, 0, 0);
        __syncthreads();
    }
    #undef STAGE

    int row0 = bm + wr*64 + lg*4;
    int col0 = bn + wc*WN + lr;
    #pragma unroll
    for (int m = 0; m < 4; ++m) {
        #pragma unroll
        for (int nn = 0; nn < NFR; ++nn) {
            int col = col0 + nn*16;
            float bv = bias[col];
            #pragma unroll
            for (int j = 0; j < 4; ++j) {
                int row = row0 + m*16 + j;
                if (row >= M) continue;
                float v = acc[m][nn][j] + bv;
                size_t idx = (size_t)row*N + col;
                if (MODE == 0) {
                    if (res1) v += res1[idx] + (float)res2[idx];
                    ((float*)Cout)[idx] = v;
                } else {
                    ((f16*)Cout)[idx] = (f16)gelu_exact(v);
                }
            }
        }
    }
}

// ---------- fused classifier head ----------
__global__ __launch_bounds__(256) void head_kernel(const float* __restrict__ h,
                                                   const float* __restrict__ W_out,
                                                   const float* __restrict__ b_out,
                                                   float* __restrict__ out) {
    int n = blockIdx.x, t = threadIdx.x;
    __shared__ float xs[HIDDEN];
    __shared__ float red[4];
    const float* hr = h + (size_t)n*SEQ*HIDDEN;
    for (int k = t; k < HIDDEN; k += 256) xs[k] = hr[k];
    __syncthreads();

    bool v3 = t < (OUTD - 768);
    int c3 = v3 ? (t + 768) : t;
    float a0 = 0.f, a1 = 0.f, a2 = 0.f, a3 = 0.f;
    #pragma unroll 8
    for (int k = 0; k < HIDDEN; ++k) {
        float xv = xs[k];
        const float* wr = W_out + (size_t)k*OUTD;
        a0 = fmaf(xv, wr[t],       a0);
        a1 = fmaf(xv, wr[t + 256], a1);
        a2 = fmaf(xv, wr[t + 512], a2);
        a3 = fmaf(xv, wr[c3],      a3);
    }
    a0 += b_out[t]; a1 += b_out[t + 256]; a2 += b_out[t + 512];
    a3 = v3 ? (a3 + b_out[t + 768]) : -1e30f;

    int wid = t >> 6, lane = t & 63;
    float mx = fmaxf(fmaxf(a0, a1), fmaxf(a2, a3));
    #pragma unroll
    for (int off = 32; off > 0; off >>= 1) mx = fmaxf(mx, __shfl_xor(mx, off));
    if (lane == 0) red[wid] = mx;
    __syncthreads();
    mx = fmaxf(fmaxf(red[0], red[1]), fmaxf(red[2], red[3]));
    __syncthreads();

    float p0 = expf(a0 - mx), p1 = expf(a1 - mx), p2 = expf(a2 - mx);
    float p3 = v3 ? expf(a3 - mx) : 0.f;
    float s = p0 + p1 + p2 + p3;
    #pragma unroll
    for (int off = 32; off > 0; off >>= 1) s += __shfl_xor(s, off);
    if (lane == 0) red[wid] = s;
    __syncthreads();
    s = red[0] + red[1] + red[2] + red[3];
    float inv = 1.0f / s;

    float* orow = out + (size_t)n*OUTD;
    orow[t]       = p0 * inv;
    orow[t + 256] = p1 * inv;
    orow[t + 512] = p2 * inv;
    if (v3) orow[t + 768] = p3 * inv;
}

extern "C" void kernel_launch(void* const* d_in, const int* in_sizes, int n_in,
                              void* d_out, int out_size, void* d_ws, size_t ws_size,
                              hipStream_t stream) {
    const float* x     = (const float*)d_in[0];
    const float* W_map = (const float*)d_in[1];
    const float* b_map = (const float*)d_in[2];
    const float* cls_t = (const float*)d_in[3];
    const float* pos   = (const float*)d_in[4];
    const float* ln1_s = (const float*)d_in[5];
    const float* ln1_b = (const float*)d_in[6];
    const float* Wq    = (const float*)d_in[7];
    const float* bq    = (const float*)d_in[8];
    const float* Wk    = (const float*)d_in[9];
    const float* bk    = (const float*)d_in[10];
    const float* Wv    = (const float*)d_in[11];
    const float* bv    = (const float*)d_in[12];
    const float* ln2_s = (const float*)d_in[13];
    const float* ln2_b = (const float*)d_in[14];
    const float* W1    = (const float*)d_in[15];
    const float* b1    = (const float*)d_in[16];
    const float* W2    = (const float*)d_in[17];
    const float* b2    = (const float*)d_in[18];
    const float* W_out = (const float*)d_in[19];
    const float* b_out = (const float*)d_in[20];
    float* out = (float*)d_out;

    const size_t LAYER_W = (size_t)HIDDEN * MLP_D;

    char* w = (char*)d_ws;
    const size_t SZ32 = (size_t)M_TOK * HIDDEN * 4;
    float* h        = (float*)w;  w += SZ32;
    float* tokens32 = (float*)w;  w += SZ32;                        // patch-embed fp32 out
    f16*   attn_out = (f16*)w;    w += (size_t)M_PAD * HIDDEN * 2;  // f16 attention residual
    f16*   mid_h    = (f16*)w;    w += (size_t)M_PAD * MLP_D * 2;
    f16*   lnh1     = (f16*)w;    w += (size_t)M_PAD * HIDDEN * 2;
    f16*   lnh2     = (f16*)w;    w += (size_t)M_PAD * HIDDEN * 2;
    f16*   WmapT    = (f16*)w;    w += (size_t)768 * 768 * 2;
    f16*   qkvT     = (f16*)w;    w += (size_t)NBLOCKS * NHEADS * 3 * 64 * 64 * 2;
    size_t base_used = (size_t)(w - (char*)d_ws);
    bool big = ws_size >= base_used + 2 * NBLOCKS * LAYER_W * 2;
    f16* W1T = (f16*)w;  w += (big ? NBLOCKS : 1) * LAYER_W * 2;
    f16* W2T = (f16*)w;  w += (big ? NBLOCKS : 1) * LAYER_W * 2;

    f16* patches_h = mid_h;
    patchify_kernel<<<BATCH*NPATCH, 256, 0, stream>>>(x, patches_h);
    {
        dim3 g(12, 12, 1);
        transT_kernel<<<g, 256, 0, stream>>>(W_map, WmapT, 768, 768);
    }
    qkvtrans_kernel<<<NBLOCKS*NHEADS*3, 256, 0, stream>>>(Wq, Wk, Wv, qkvT);
    if (big) {
        dim3 g1(MLP_D/64, HIDDEN/64, NBLOCKS);
        transT_kernel<<<g1, 256, 0, stream>>>(W1, W1T, HIDDEN, MLP_D);
        dim3 g2(HIDDEN/64, MLP_D/64, NBLOCKS);
        transT_kernel<<<g2, 256, 0, stream>>>(W2, W2T, MLP_D, HIDDEN);
    }
    // tokens = patches @ W_map + b_map -> tokens32 (fp32); M=6272=49*128 exact
    hgemm_kernel<0,64><<<49*12, 256, 0, stream>>>(patches_h, WmapT, b_map,
                                                  nullptr, nullptr,
                                                  (void*)tokens32, BATCH*NPATCH, 768, 768, 12);
    assemble_kernel<<<M_TOK, 256, 0, stream>>>(tokens32, cls_t, pos, h);

    for (int blk = 0; blk < NBLOCKS; ++blk) {
        f16* w1t = big ? (W1T + (size_t)blk * LAYER_W) : W1T;
        f16* w2t = big ? (W2T + (size_t)blk * LAYER_W) : W2T;
        layernorm2_kernel<<<M_TOK/4, 256, 0, stream>>>(h,
            ln1_s + blk*768, ln1_b + blk*768, ln2_s + blk*768, ln2_b + blk*768,
            lnh1, lnh2);
        if (!big) {
            dim3 g(MLP_D/32, HIDDEN/32, 2);
            convtrans2_kernel<<<g, 256, 0, stream>>>(W1 + (size_t)blk*LAYER_W,
                                                     W2 + (size_t)blk*LAYER_W, w1t, w2t);
        }
        {
            dim3 g(BATCH, NHEADS);
            fused_attn_kernel<<<g, 512, 0, stream>>>(lnh1,
                qkvT + (size_t)blk*NHEADS*3*4096,
                bq + (size_t)blk*768, bk + (size_t)blk*768, bv + (size_t)blk*768,
                attn_out);
        }
        // mid = gelu(lnh2 @ W1 + b1), N=3072: grid 50x48 (round-12 best)
        hgemm_kernel<1,64><<<50*48, 256, 0, stream>>>(lnh2, w1t, b1 + (size_t)blk*MLP_D,
                                                      nullptr, nullptr,
                                                      (void*)mid_h, M_TOK, MLP_D, 768, 48);
        // h = h + attn_out(f16) + (mid @ W2 + b2), N=768: grid 50x12
        hgemm_kernel<0,64><<<50*12, 256, 0, stream>>>(mid_h, w2t, b2 + (size_t)blk*HIDDEN,
                                                      h, attn_out,
                                                      (void*)h, M_TOK, HIDDEN, MLP_D, 12);
    }

    head_kernel<<<BATCH, 256, 0, stream>>>(h, W_out, b_out, out);
}